// Round 3
// baseline (174.977 us; speedup 1.0000x reference)
//
#include <hip/hip_runtime.h>

typedef unsigned short u16;
typedef __attribute__((ext_vector_type(8))) short short8;
typedef __attribute__((ext_vector_type(4))) float floatx4;

// ---------- constants ----------
#define N_ENT   512
#define P_PAIRS 15872
#define E_DIM   768
#define D2      1536          // 2*E
#define OUT_ENT   (512*1536)        // 786432
#define OUT_REL   (15872*512)       // 8126464

#define BM 128
#define BN 128
#define BK 32

__device__ __forceinline__ u16 f2bf(float f){
    union { float f; unsigned u; } v; v.f = f;
    unsigned r = v.u + 0x7fffu + ((v.u >> 16) & 1u);   // RNE
    return (u16)(r >> 16);
}

// ---------- transpose + fp32->bf16: src[R][C] f32 -> dst[C][R] bf16 ----------
__global__ void transpose_k(const float* __restrict__ src, u16* __restrict__ dst,
                            int R, int C) {
    __shared__ float tile[32][33];
    const int bx = blockIdx.x * 32;   // col tile
    const int by = blockIdx.y * 32;   // row tile
    const int tx = threadIdx.x, ty = threadIdx.y;  // (32, 8)
#pragma unroll
    for (int i = 0; i < 32; i += 8)
        tile[ty + i][tx] = src[(size_t)(by + ty + i) * C + bx + tx];
    __syncthreads();
#pragma unroll
    for (int i = 0; i < 32; i += 8)
        dst[(size_t)(bx + ty + i) * R + by + tx] = f2bf(tile[tx][ty + i]);
}

// ---------- gather entity_representation [512, 1536] ----------
// out0 (fp32, exact copy) + EntB (bf16, for MFMA)
__global__ void gather_k(const float* __restrict__ x, const int* __restrict__ ann,
                         float* __restrict__ entF, u16* __restrict__ entB) {
    const int e = blockIdx.x;            // 0..511
    const int t = threadIdx.x;           // 0..383 (6 waves)
    const int half = t / 192;            // which annotation token
    const int chunk = t % 192;           // 192 float4 chunks of 768 floats
    const int tok = ann[e * 2 + half];
    const int b = e >> 5;
    const float4 v = ((const float4*)(x + (size_t)(b * 512 + tok) * E_DIM))[chunk];
    ((float4*)(entF + (size_t)e * D2 + half * E_DIM))[chunk] = v;
    ushort4 o;
    o.x = f2bf(v.x); o.y = f2bf(v.y); o.z = f2bf(v.z); o.w = f2bf(v.w);
    ((ushort4*)(entB + (size_t)e * D2 + half * E_DIM))[chunk] = o;
}

// ---------- GEMM: U/V/Us/Vs = EntB[512,1536] @ {W1T,Ws1T} -> fp32 [4][512][512] ----------
// grid (4, 16): x = m-tile, y = n-tile over 2048 virtual cols
__global__ __launch_bounds__(256)
void gemm_uv(const u16* __restrict__ Ent, const u16* __restrict__ W1T,
             const u16* __restrict__ Ws1T, float* __restrict__ UV) {
    __shared__ __align__(16) u16 As[BM * BK];
    __shared__ __align__(16) u16 Bs[BN * BK];
    const int t = threadIdx.x;
    const int m0 = blockIdx.x * BM;
    const int n0g = blockIdx.y * BN;        // 0..2047
    const int g = n0g >> 9;                 // 0..3 : U,V,Us,Vs
    const int n0 = n0g & 511;
    const u16* WT = (g < 2) ? W1T : Ws1T;   // [512, 3072] rows = output col
    const int koff = (g & 1) * D2;          // top/bottom half of original W

    const int wave = t >> 6, lane = t & 63;
    const int wm = (wave >> 1) * 64, wn = (wave & 1) * 64;
    const int l15 = lane & 15, quad = lane >> 4;
    const int srow = t >> 2;                // 0..63
    const int soff = (t & 3) * 8;           // bf16 elems (16B)

    floatx4 acc[4][4] = {};
    for (int k0 = 0; k0 < D2; k0 += BK) {
        uint4 a0 = *(const uint4*)(Ent + (size_t)(m0 + srow) * D2 + k0 + soff);
        uint4 a1 = *(const uint4*)(Ent + (size_t)(m0 + 64 + srow) * D2 + k0 + soff);
        uint4 b0 = *(const uint4*)(WT + (size_t)(n0 + srow) * 3072 + koff + k0 + soff);
        uint4 b1 = *(const uint4*)(WT + (size_t)(n0 + 64 + srow) * 3072 + koff + k0 + soff);
        __syncthreads();
        *(uint4*)(As + srow * BK + soff) = a0;
        *(uint4*)(As + (64 + srow) * BK + soff) = a1;
        *(uint4*)(Bs + srow * BK + soff) = b0;
        *(uint4*)(Bs + (64 + srow) * BK + soff) = b1;
        __syncthreads();
        short8 af[4], bfr[4];
#pragma unroll
        for (int i = 0; i < 4; i++) {
            af[i]  = *(const short8*)(As + (wm + i * 16 + l15) * BK + quad * 8);
            bfr[i] = *(const short8*)(Bs + (wn + i * 16 + l15) * BK + quad * 8);
        }
#pragma unroll
        for (int i = 0; i < 4; i++)
#pragma unroll
            for (int j = 0; j < 4; j++)
                acc[i][j] = __builtin_amdgcn_mfma_f32_16x16x32_bf16(af[i], bfr[j], acc[i][j], 0, 0, 0);
    }
    float* outg = UV + (size_t)g * (512 * 512);
#pragma unroll
    for (int j = 0; j < 4; j++) {
        const int col = n0 + wn + j * 16 + l15;
#pragma unroll
        for (int i = 0; i < 4; i++) {
            const int rowb = m0 + wm + i * 16 + quad * 4;
#pragma unroll
            for (int r = 0; r < 4; r++)
                outg[(size_t)(rowb + r) * 512 + col] = acc[i][j][r];
        }
    }
}

// ---------- per-pair: H = relu(U[l]+V[r]+b1) -> bf16 ws ; score = |relu(Us[l]+Vs[r]+bs1) . Ws2 + bs2| -> fp32 out ----------
__global__ __launch_bounds__(256)
void pair_k(const float* __restrict__ UV, const int* __restrict__ left,
            const int* __restrict__ right, const float* __restrict__ b1,
            const float* __restrict__ bs1, const float* __restrict__ Ws2,
            const float* __restrict__ bs2, u16* __restrict__ Hrel,
            float* __restrict__ score) {
    const int p = blockIdx.x * 4 + (threadIdx.x >> 6);
    const int lane = threadIdx.x & 63;
    const int l = left[p], r = right[p];
    const float* U  = UV + (size_t)l * 512;
    const float* V  = UV + 1 * 262144 + (size_t)r * 512;
    const float* Us = UV + 2 * 262144 + (size_t)l * 512;
    const float* Vs = UV + 3 * 262144 + (size_t)r * 512;
    float acc = 0.f;
#pragma unroll
    for (int s = 0; s < 8; s++) {
        const int k = lane + s * 64;
        float h = U[k] + V[k] + b1[k];
        Hrel[(size_t)p * 512 + k] = f2bf(fmaxf(h, 0.f));
        float hs = Us[k] + Vs[k] + bs1[k];
        acc += fmaxf(hs, 0.f) * Ws2[k];
    }
#pragma unroll
    for (int off = 32; off; off >>= 1) acc += __shfl_down(acc, off, 64);
    if (lane == 0) score[p] = fabsf(acc + bs2[0]);
}

// ---------- GEMM: rel = Hrel[15872,512] @ W2[512,512] + b2 -> fp32 out ----------
// grid (124, 4)
__global__ __launch_bounds__(256)
void gemm_rel(const u16* __restrict__ A, const u16* __restrict__ BT,
              const float* __restrict__ b2, float* __restrict__ Cout) {
    __shared__ __align__(16) u16 As[BM * BK];
    __shared__ __align__(16) u16 Bs[BN * BK];
    const int t = threadIdx.x;
    const int m0 = blockIdx.x * BM;
    const int n0 = blockIdx.y * BN;
    const int wave = t >> 6, lane = t & 63;
    const int wm = (wave >> 1) * 64, wn = (wave & 1) * 64;
    const int l15 = lane & 15, quad = lane >> 4;
    const int srow = t >> 2;
    const int soff = (t & 3) * 8;

    floatx4 acc[4][4] = {};
    for (int k0 = 0; k0 < 512; k0 += BK) {
        uint4 a0 = *(const uint4*)(A + (size_t)(m0 + srow) * 512 + k0 + soff);
        uint4 a1 = *(const uint4*)(A + (size_t)(m0 + 64 + srow) * 512 + k0 + soff);
        uint4 b0 = *(const uint4*)(BT + (size_t)(n0 + srow) * 512 + k0 + soff);
        uint4 b1v = *(const uint4*)(BT + (size_t)(n0 + 64 + srow) * 512 + k0 + soff);
        __syncthreads();
        *(uint4*)(As + srow * BK + soff) = a0;
        *(uint4*)(As + (64 + srow) * BK + soff) = a1;
        *(uint4*)(Bs + srow * BK + soff) = b0;
        *(uint4*)(Bs + (64 + srow) * BK + soff) = b1v;
        __syncthreads();
        short8 af[4], bfr[4];
#pragma unroll
        for (int i = 0; i < 4; i++) {
            af[i]  = *(const short8*)(As + (wm + i * 16 + l15) * BK + quad * 8);
            bfr[i] = *(const short8*)(Bs + (wn + i * 16 + l15) * BK + quad * 8);
        }
#pragma unroll
        for (int i = 0; i < 4; i++)
#pragma unroll
            for (int j = 0; j < 4; j++)
                acc[i][j] = __builtin_amdgcn_mfma_f32_16x16x32_bf16(af[i], bfr[j], acc[i][j], 0, 0, 0);
    }
#pragma unroll
    for (int j = 0; j < 4; j++) {
        const int col = n0 + wn + j * 16 + l15;
        const float bias = b2[col];
#pragma unroll
        for (int i = 0; i < 4; i++) {
            const int rowb = m0 + wm + i * 16 + quad * 4;
#pragma unroll
            for (int r = 0; r < 4; r++)
                Cout[(size_t)(rowb + r) * 512 + col] = acc[i][j][r] + bias;
        }
    }
}

extern "C" void kernel_launch(void* const* d_in, const int* in_sizes, int n_in,
                              void* d_out, int out_size, void* d_ws, size_t ws_size,
                              hipStream_t stream) {
    const float* x   = (const float*)d_in[0];
    const int* ann   = (const int*)d_in[3];
    const int* left  = (const int*)d_in[5];
    const int* right = (const int*)d_in[6];
    const float* W1  = (const float*)d_in[7];
    const float* b1  = (const float*)d_in[8];
    const float* W2  = (const float*)d_in[9];
    const float* b2  = (const float*)d_in[10];
    const float* Ws1 = (const float*)d_in[11];
    const float* bs1 = (const float*)d_in[12];
    const float* Ws2 = (const float*)d_in[13];
    const float* bs2 = (const float*)d_in[14];

    float* out = (float*)d_out;
    float* entF = out;                       // [512*1536] fp32 (output 0)
    float* rel  = out + OUT_ENT;             // [15872*512] fp32 (output 1)
    float* sco  = out + OUT_ENT + OUT_REL;   // [15872] fp32 (output 2)

    // workspace layout (16B aligned), ~28.8 MB total
    u16* W1T  = (u16*)d_ws;                  // 512*3072 bf16
    u16* Ws1T = W1T + 512 * 3072;            // 512*3072 bf16
    u16* W2T  = Ws1T + 512 * 3072;           // 512*512 bf16
    u16* EntB = W2T + 512 * 512;             // 512*1536 bf16
    float* UV = (float*)(EntB + 512 * 1536); // 4 * 512*512 fp32
    u16* Hrel = (u16*)(UV + 4 * 512 * 512);  // 15872*512 bf16

    transpose_k<<<dim3(16, 96), dim3(32, 8), 0, stream>>>(W1, W1T, 3072, 512);
    transpose_k<<<dim3(16, 96), dim3(32, 8), 0, stream>>>(Ws1, Ws1T, 3072, 512);
    transpose_k<<<dim3(16, 16), dim3(32, 8), 0, stream>>>(W2, W2T, 512, 512);
    gather_k<<<512, 384, 0, stream>>>(x, ann, entF, EntB);
    gemm_uv<<<dim3(4, 16), 256, 0, stream>>>(EntB, W1T, Ws1T, UV);
    pair_k<<<P_PAIRS / 4, 256, 0, stream>>>(UV, left, right, b1, bs1, Ws2, bs2, Hrel, sco);
    gemm_rel<<<dim3(124, 4), 256, 0, stream>>>(Hrel, W2T, b2, rel);
}

// Round 4
// 165.512 us; speedup vs baseline: 1.0572x; 1.0572x over previous
//
#include <hip/hip_runtime.h>

typedef unsigned short u16;
typedef __attribute__((ext_vector_type(8))) short short8;
typedef __attribute__((ext_vector_type(4))) float floatx4;

#define P_PAIRS 15872
#define E_DIM   768
#define D2      1536
#define OUT_ENT   (512*1536)
#define OUT_REL   (15872*512)

__device__ __forceinline__ u16 f2bf(float f){
    union { float f; unsigned u; } v; v.f = f;
    unsigned r = v.u + 0x7fffu + ((v.u >> 16) & 1u);   // RNE
    return (u16)(r >> 16);
}
__device__ __forceinline__ unsigned pack2(float a, float b){
    return (unsigned)f2bf(a) | ((unsigned)f2bf(b) << 16);
}
// async global->LDS, 16B per lane; lds base must be wave-uniform (lane*16 auto-added)
__device__ __forceinline__ void async_ld16(const void* g, void* lds_base){
    __builtin_amdgcn_global_load_lds(
        (const __attribute__((address_space(1))) unsigned*)g,
        (__attribute__((address_space(3))) unsigned*)lds_base, 16, 0, 0);
}

// ================= prep: W1T, Ws1T, W2T transposes (+bf16) and entity gather =================
// grid 3840 x 256 threads.  blocks: [0,1536) W1T | [1536,3072) Ws1T | [3072,3328) W2T | [3328,3840) gather
__global__ __launch_bounds__(256)
void prep_k(const float* __restrict__ W1, const float* __restrict__ Ws1,
            const float* __restrict__ W2, const float* __restrict__ x,
            const int* __restrict__ ann,
            u16* __restrict__ W1T, u16* __restrict__ Ws1T, u16* __restrict__ W2T,
            float* __restrict__ entF, u16* __restrict__ entB) {
    const int bid = blockIdx.x;
    const int t = threadIdx.x;
    if (bid < 3328) {
        __shared__ float tile[32][33];
        const float* src; u16* dst; int R, C, b;
        if (bid < 1536)      { src = W1;  dst = W1T;  R = 3072; C = 512; b = bid; }
        else if (bid < 3072) { src = Ws1; dst = Ws1T; R = 3072; C = 512; b = bid - 1536; }
        else                 { src = W2;  dst = W2T;  R = 512;  C = 512; b = bid - 3072; }
        const int bx = (b & 15) * 32;
        const int by = (b >> 4) * 32;
        const int tx = t & 31, ty = t >> 5;
#pragma unroll
        for (int i = 0; i < 32; i += 8)
            tile[ty + i][tx] = src[(size_t)(by + ty + i) * C + bx + tx];
        __syncthreads();
#pragma unroll
        for (int i = 0; i < 32; i += 8)
            dst[(size_t)(bx + ty + i) * R + by + tx] = f2bf(tile[tx][ty + i]);
    } else {
        const int e = bid - 3328;            // 0..511
#pragma unroll
        for (int pass = 0; pass < 2; pass++) {
            const int c = t + pass * 256;    // float4 chunk 0..383
            if (c >= 384) break;
            const int half = c / 192;
            const int tok = ann[e * 2 + half];
            const int b = e >> 5;
            const float4 v = ((const float4*)(x + (size_t)(b * 512 + tok) * E_DIM))[c % 192];
            ((float4*)(entF + (size_t)e * D2))[c] = v;
            uint2 o; o.x = pack2(v.x, v.y); o.y = pack2(v.z, v.w);
            ((uint2*)(entB + (size_t)e * D2))[c] = o;
        }
    }
}

// ================= gemm_uv: UV[4][512][512] = EntB @ {W1T|Ws1T} halves, 64x64 tiles =================
// grid 256: bid&7 = m-tile, bid>>3 = n-tile over 2048 virtual cols
__global__ __launch_bounds__(256)
void gemm_uv(const u16* __restrict__ Ent, const u16* __restrict__ W1T,
             const u16* __restrict__ Ws1T, float* __restrict__ UV) {
    __shared__ __align__(16) u16 As[64 * 32];
    __shared__ __align__(16) u16 Bs[64 * 32];
    const int t = threadIdx.x;
    const int bid = blockIdx.x;
    const int m0 = (bid & 7) * 64;
    const int n0g = (bid >> 3) * 64;
    const int g = n0g >> 9;
    const int n0 = n0g & 511;
    const u16* WT = (g < 2) ? W1T : Ws1T;
    const int koff = (g & 1) * D2;

    const int wave = t >> 6, lane = t & 63;
    const int wm = (wave >> 1) * 32, wn = (wave & 1) * 32;
    const int l15 = lane & 15, quad = lane >> 4;
    const int srow = t >> 2;            // 0..63
    const int sk = (t & 3) * 8;

    const u16* gA = Ent + (size_t)(m0 + srow) * D2 + sk;
    const u16* gB = WT + (size_t)(n0 + srow) * 3072 + koff + sk;
    u16* lA = As + wave * 512;          // wave-uniform, bytes = wave*1024
    u16* lB = Bs + wave * 512;

    floatx4 acc[2][2] = {};
    for (int k0 = 0; k0 < D2; k0 += 32) {
        __syncthreads();
        async_ld16(gA + k0, lA);
        async_ld16(gB + k0, lB);
        __syncthreads();
        short8 af[2], bf[2];
#pragma unroll
        for (int i = 0; i < 2; i++) {
            af[i] = *(const short8*)(As + (wm + i * 16 + l15) * 32 + quad * 8);
            bf[i] = *(const short8*)(Bs + (wn + i * 16 + l15) * 32 + quad * 8);
        }
#pragma unroll
        for (int i = 0; i < 2; i++)
#pragma unroll
            for (int j = 0; j < 2; j++)
                acc[i][j] = __builtin_amdgcn_mfma_f32_16x16x32_bf16(af[i], bf[j], acc[i][j], 0, 0, 0);
    }
    float* outg = UV + (size_t)g * 262144;
#pragma unroll
    for (int j = 0; j < 2; j++) {
        const int col = n0 + wn + j * 16 + l15;
#pragma unroll
        for (int i = 0; i < 2; i++) {
            const int rowb = m0 + wm + i * 16 + quad * 4;
#pragma unroll
            for (int r = 0; r < 4; r++)
                outg[(size_t)(rowb + r) * 512 + col] = acc[i][j][r];
        }
    }
}

// ================= rel_score: blocks [0,496) fused-H GEMM; [496,992) scores =================
__global__ __launch_bounds__(256)
void rel_score_k(const float* __restrict__ UV, const int* __restrict__ left,
                 const int* __restrict__ right, const float* __restrict__ b1,
                 const float* __restrict__ bs1, const float* __restrict__ Ws2,
                 const float* __restrict__ bs2, const u16* __restrict__ W2T,
                 const float* __restrict__ b2, float* __restrict__ rel,
                 float* __restrict__ score) {
    const int bid = blockIdx.x;
    const int t = threadIdx.x;
    const int wave = t >> 6, lane = t & 63;

    if (bid < 496) {
        // ---- GEMM: rel[m0:m0+128, n0:n0+128] = relu(U[l]+V[r]+b1) @ W2 + b2 ----
        __shared__ __align__(16) u16 As[128 * 32];
        __shared__ __align__(16) u16 Bs[128 * 32];
        const int m0 = (bid >> 2) * 128;
        const int n0 = (bid & 3) * 128;
        const int wm = (wave >> 1) * 64, wn = (wave & 1) * 64;
        const int l15 = lane & 15, quad = lane >> 4;

        // A staging role: row = t>>1 (0..127), k halves of 16
        const int arow = t >> 1;
        const int koff16 = (t & 1) * 16;
        const int li = left[m0 + arow], ri = right[m0 + arow];
        const float4* Up = (const float4*)(UV + (size_t)li * 512 + koff16);
        const float4* Vp = (const float4*)(UV + 262144 + (size_t)ri * 512 + koff16);
        const float4* B1 = (const float4*)(b1 + koff16);
        // B staging role: two 4KB async ops, slots t*16 bytes and 4096 + t*16
        const int brow = t >> 2;
        const int bk = (t & 3) * 8;
        const u16* gB0 = W2T + (size_t)(n0 + brow) * 512 + bk;
        const u16* gB1 = W2T + (size_t)(n0 + 64 + brow) * 512 + bk;
        u16* lB0 = Bs + wave * 512;
        u16* lB1 = Bs + 2048 + wave * 512;
        uint4* aDst = (uint4*)(As + t * 16);   // bytes t*32: row arow, k koff16..+15

        floatx4 acc[4][4] = {};
        for (int k0 = 0; k0 < 512; k0 += 32) {
            float4 uu[4], vv[4], bb[4];
            const int kq = k0 >> 2;
#pragma unroll
            for (int j = 0; j < 4; j++) {
                uu[j] = Up[kq + j]; vv[j] = Vp[kq + j]; bb[j] = B1[kq + j];
            }
            __syncthreads();
            async_ld16(gB0 + k0, lB0);
            async_ld16(gB1 + k0, lB1);
            uint4 h0, h1;
            {
                float4 h;
                h.x = fmaxf(uu[0].x + vv[0].x + bb[0].x, 0.f);
                h.y = fmaxf(uu[0].y + vv[0].y + bb[0].y, 0.f);
                h.z = fmaxf(uu[0].z + vv[0].z + bb[0].z, 0.f);
                h.w = fmaxf(uu[0].w + vv[0].w + bb[0].w, 0.f);
                h0.x = pack2(h.x, h.y); h0.y = pack2(h.z, h.w);
                h.x = fmaxf(uu[1].x + vv[1].x + bb[1].x, 0.f);
                h.y = fmaxf(uu[1].y + vv[1].y + bb[1].y, 0.f);
                h.z = fmaxf(uu[1].z + vv[1].z + bb[1].z, 0.f);
                h.w = fmaxf(uu[1].w + vv[1].w + bb[1].w, 0.f);
                h0.z = pack2(h.x, h.y); h0.w = pack2(h.z, h.w);
                h.x = fmaxf(uu[2].x + vv[2].x + bb[2].x, 0.f);
                h.y = fmaxf(uu[2].y + vv[2].y + bb[2].y, 0.f);
                h.z = fmaxf(uu[2].z + vv[2].z + bb[2].z, 0.f);
                h.w = fmaxf(uu[2].w + vv[2].w + bb[2].w, 0.f);
                h1.x = pack2(h.x, h.y); h1.y = pack2(h.z, h.w);
                h.x = fmaxf(uu[3].x + vv[3].x + bb[3].x, 0.f);
                h.y = fmaxf(uu[3].y + vv[3].y + bb[3].y, 0.f);
                h.z = fmaxf(uu[3].z + vv[3].z + bb[3].z, 0.f);
                h.w = fmaxf(uu[3].w + vv[3].w + bb[3].w, 0.f);
                h1.z = pack2(h.x, h.y); h1.w = pack2(h.z, h.w);
            }
            aDst[0] = h0; aDst[1] = h1;
            __syncthreads();
            short8 af[4], bf[4];
#pragma unroll
            for (int i = 0; i < 4; i++) {
                af[i] = *(const short8*)(As + (wm + i * 16 + l15) * 32 + quad * 8);
                bf[i] = *(const short8*)(Bs + (wn + i * 16 + l15) * 32 + quad * 8);
            }
#pragma unroll
            for (int i = 0; i < 4; i++)
#pragma unroll
                for (int j = 0; j < 4; j++)
                    acc[i][j] = __builtin_amdgcn_mfma_f32_16x16x32_bf16(af[i], bf[j], acc[i][j], 0, 0, 0);
        }
#pragma unroll
        for (int j = 0; j < 4; j++) {
            const int col = n0 + wn + j * 16 + l15;
            const float bias = b2[col];
#pragma unroll
            for (int i = 0; i < 4; i++) {
                const int rowb = m0 + wm + i * 16 + quad * 4;
#pragma unroll
                for (int r = 0; r < 4; r++)
                    rel[(size_t)(rowb + r) * 512 + col] = acc[i][j][r] + bias;
            }
        }
    } else {
        // ---- scores: 32 pairs per block, 8 per wave ----
        const int pid0 = (bid - 496) * 32 + wave * 8;
        const float4* Wsp = (const float4*)(Ws2 + lane * 8);
        const float4* Bsp = (const float4*)(bs1 + lane * 8);
        const float4 w0 = Wsp[0], w1 = Wsp[1];
        const float4 s0 = Bsp[0], s1 = Bsp[1];
        const float bias = bs2[0];
#pragma unroll
        for (int it = 0; it < 8; it++) {
            const int p = pid0 + it;
            const int l = left[p], r = right[p];
            const float4* us = (const float4*)(UV + 2 * 262144 + (size_t)l * 512 + lane * 8);
            const float4* vs = (const float4*)(UV + 3 * 262144 + (size_t)r * 512 + lane * 8);
            const float4 a0 = us[0], a1 = us[1];
            const float4 c0 = vs[0], c1 = vs[1];
            float acc;
            acc  = fmaxf(a0.x + c0.x + s0.x, 0.f) * w0.x;
            acc += fmaxf(a0.y + c0.y + s0.y, 0.f) * w0.y;
            acc += fmaxf(a0.z + c0.z + s0.z, 0.f) * w0.z;
            acc += fmaxf(a0.w + c0.w + s0.w, 0.f) * w0.w;
            acc += fmaxf(a1.x + c1.x + s1.x, 0.f) * w1.x;
            acc += fmaxf(a1.y + c1.y + s1.y, 0.f) * w1.y;
            acc += fmaxf(a1.z + c1.z + s1.z, 0.f) * w1.z;
            acc += fmaxf(a1.w + c1.w + s1.w, 0.f) * w1.w;
#pragma unroll
            for (int off = 32; off; off >>= 1) acc += __shfl_down(acc, off, 64);
            if (lane == 0) score[p] = fabsf(acc + bias);
        }
    }
}

extern "C" void kernel_launch(void* const* d_in, const int* in_sizes, int n_in,
                              void* d_out, int out_size, void* d_ws, size_t ws_size,
                              hipStream_t stream) {
    const float* x   = (const float*)d_in[0];
    const int* ann   = (const int*)d_in[3];
    const int* left  = (const int*)d_in[5];
    const int* right = (const int*)d_in[6];
    const float* W1  = (const float*)d_in[7];
    const float* b1  = (const float*)d_in[8];
    const float* W2  = (const float*)d_in[9];
    const float* b2  = (const float*)d_in[10];
    const float* Ws1 = (const float*)d_in[11];
    const float* bs1 = (const float*)d_in[12];
    const float* Ws2 = (const float*)d_in[13];
    const float* bs2 = (const float*)d_in[14];

    float* out = (float*)d_out;
    float* entF = out;                       // output 0 (exact fp32 copy)
    float* rel  = out + OUT_ENT;             // output 1
    float* sco  = out + OUT_ENT + OUT_REL;   // output 2

    u16* W1T  = (u16*)d_ws;                  // 512*3072 bf16 (B^T: row = out col)
    u16* Ws1T = W1T + 512 * 3072;
    u16* W2T  = Ws1T + 512 * 3072;           // 512*512 bf16
    u16* EntB = W2T + 512 * 512;             // 512*1536 bf16
    float* UV = (float*)(EntB + 512 * 1536); // [4][512][512] fp32: U,V,Us,Vs

    prep_k<<<3840, 256, 0, stream>>>(W1, Ws1, W2, x, ann, W1T, Ws1T, W2T, entF, EntB);
    gemm_uv<<<256, 256, 0, stream>>>(EntB, W1T, Ws1T, UV);
    rel_score_k<<<992, 256, 0, stream>>>(UV, left, right, b1, bs1, Ws2, bs2, W2T, b2, rel, sco);
}

// Round 5
// 163.050 us; speedup vs baseline: 1.0731x; 1.0151x over previous
//
#include <hip/hip_runtime.h>

typedef unsigned short u16;
typedef __attribute__((ext_vector_type(8))) short short8;
typedef __attribute__((ext_vector_type(4))) float floatx4;

#define P_PAIRS 15872
#define E_DIM   768
#define D2      1536
#define OUT_ENT   (512*1536)
#define OUT_REL   (15872*512)

__device__ __forceinline__ u16 f2bf(float f){
    union { float f; unsigned u; } v; v.f = f;
    unsigned r = v.u + 0x7fffu + ((v.u >> 16) & 1u);   // RNE
    return (u16)(r >> 16);
}
__device__ __forceinline__ unsigned pack2(float a, float b){
    return (unsigned)f2bf(a) | ((unsigned)f2bf(b) << 16);
}
// async global->LDS, 16B per lane; lds base wave-uniform (lane*16 auto-added)
__device__ __forceinline__ void async_ld16(const void* g, void* lds_base){
    __builtin_amdgcn_global_load_lds(
        (const __attribute__((address_space(1))) unsigned*)g,
        (__attribute__((address_space(3))) unsigned*)lds_base, 16, 0, 0);
}

// ================= prep: W1T, Ws1T, W2T transposes (+bf16) and entity gather =================
__global__ __launch_bounds__(256)
void prep_k(const float* __restrict__ W1, const float* __restrict__ Ws1,
            const float* __restrict__ W2, const float* __restrict__ x,
            const int* __restrict__ ann,
            u16* __restrict__ W1T, u16* __restrict__ Ws1T, u16* __restrict__ W2T,
            float* __restrict__ entF, u16* __restrict__ entB) {
    const int bid = blockIdx.x;
    const int t = threadIdx.x;
    if (bid < 3328) {
        __shared__ float tile[32][33];
        const float* src; u16* dst; int R, C, b;
        if (bid < 1536)      { src = W1;  dst = W1T;  R = 3072; C = 512; b = bid; }
        else if (bid < 3072) { src = Ws1; dst = Ws1T; R = 3072; C = 512; b = bid - 1536; }
        else                 { src = W2;  dst = W2T;  R = 512;  C = 512; b = bid - 3072; }
        const int bx = (b & 15) * 32;
        const int by = (b >> 4) * 32;
        const int tx = t & 31, ty = t >> 5;
#pragma unroll
        for (int i = 0; i < 32; i += 8)
            tile[ty + i][tx] = src[(size_t)(by + ty + i) * C + bx + tx];
        __syncthreads();
#pragma unroll
        for (int i = 0; i < 32; i += 8)
            dst[(size_t)(bx + ty + i) * R + by + tx] = f2bf(tile[tx][ty + i]);
    } else {
        const int e = bid - 3328;            // 0..511
#pragma unroll
        for (int pass = 0; pass < 2; pass++) {
            const int c = t + pass * 256;    // float4 chunk 0..383
            if (c >= 384) break;
            const int half = c / 192;
            const int tok = ann[e * 2 + half];
            const int b = e >> 5;
            const float4 v = ((const float4*)(x + (size_t)(b * 512 + tok) * E_DIM))[c % 192];
            ((float4*)(entF + (size_t)e * D2))[c] = v;
            uint2 o; o.x = pack2(v.x, v.y); o.y = pack2(v.z, v.w);
            ((uint2*)(entB + (size_t)e * D2))[c] = o;
        }
    }
}

// ================= gemm_uv: UV[4][512][512] = EntB @ {W1T|Ws1T} =================
// 64x64 tiles, BK=64, double-buffered LDS, XOR-swizzled (conflict-free).
// biases folded: g==0 adds b1[col] (U), g==2 adds bs1[col] (Us).
__global__ __launch_bounds__(256)
void gemm_uv(const u16* __restrict__ Ent, const u16* __restrict__ W1T,
             const u16* __restrict__ Ws1T, const float* __restrict__ b1,
             const float* __restrict__ bs1, float* __restrict__ UV) {
    __shared__ __align__(16) u16 As[2][64 * 64];
    __shared__ __align__(16) u16 Bs[2][64 * 64];
    const int t = threadIdx.x;
    const int bid = blockIdx.x;
    const int m0 = (bid & 7) * 64;
    const int n0g = (bid >> 3) * 64;
    const int g = n0g >> 9;
    const int n0 = n0g & 511;
    const u16* WT = (g < 2) ? W1T : Ws1T;
    const int koff = (g & 1) * D2;

    const int wave = t >> 6, lane = t & 63;
    const int wm = (wave >> 1) * 32, wn = (wave & 1) * 32;
    const int l15 = lane & 15, quad = lane >> 4;

    // staging: wave w covers chunks 2w,2w+1 (rows 16w..16w+15); lane's logical
    // slot: row = c*8 + (lane>>3), k8 = (lane&7) ^ (lane>>3)  [XOR swizzle]
    const int lr = lane >> 3;
    const int k8 = (lane & 7) ^ lr;
    const int rowA0 = wave * 16 + lr;
    const u16* gA0 = Ent + (size_t)(m0 + rowA0) * D2 + k8 * 8;
    const u16* gA1 = Ent + (size_t)(m0 + rowA0 + 8) * D2 + k8 * 8;
    const u16* gB0 = WT + (size_t)(n0 + rowA0) * 3072 + koff + k8 * 8;
    const u16* gB1 = WT + (size_t)(n0 + rowA0 + 8) * 3072 + koff + k8 * 8;
    const int lofs0 = wave * 1024, lofs1 = wave * 1024 + 512;

    floatx4 acc[2][2] = {};
    // preload k=0 into buf 0
    async_ld16(gA0, As[0] + lofs0);
    async_ld16(gA1, As[0] + lofs1);
    async_ld16(gB0, Bs[0] + lofs0);
    async_ld16(gB1, Bs[0] + lofs1);
    for (int i = 0; i < 24; i++) {
        const int cur = i & 1;
        __syncthreads();                       // buf[cur] ready; buf[cur^1] free
        if (i + 1 < 24) {
            const int k1 = (i + 1) * 64;
            async_ld16(gA0 + k1, As[cur ^ 1] + lofs0);
            async_ld16(gA1 + k1, As[cur ^ 1] + lofs1);
            async_ld16(gB0 + k1, Bs[cur ^ 1] + lofs0);
            async_ld16(gB1 + k1, Bs[cur ^ 1] + lofs1);
        }
        const u16* Ac = As[cur];
        const u16* Bc = Bs[cur];
#pragma unroll
        for (int kk = 0; kk < 2; kk++) {       // sub-k 0, 32
            short8 af[2], bf[2];
#pragma unroll
            for (int i2 = 0; i2 < 2; i2++) {
                const int ra = wm + i2 * 16 + l15;
                af[i2] = *(const short8*)(Ac + (ra * 8 + ((quad + kk * 4) ^ (ra & 7))) * 8);
                const int rb = wn + i2 * 16 + l15;
                bf[i2] = *(const short8*)(Bc + (rb * 8 + ((quad + kk * 4) ^ (rb & 7))) * 8);
            }
#pragma unroll
            for (int i2 = 0; i2 < 2; i2++)
#pragma unroll
                for (int j2 = 0; j2 < 2; j2++)
                    acc[i2][j2] = __builtin_amdgcn_mfma_f32_16x16x32_bf16(af[i2], bf[j2], acc[i2][j2], 0, 0, 0);
        }
    }
    float* outg = UV + (size_t)g * 262144;
#pragma unroll
    for (int j = 0; j < 2; j++) {
        const int col = n0 + wn + j * 16 + l15;
        const float bias = (g == 0) ? b1[col] : (g == 2) ? bs1[col] : 0.f;
#pragma unroll
        for (int i = 0; i < 2; i++) {
            const int rowb = m0 + wm + i * 16 + quad * 4;
#pragma unroll
            for (int r = 0; r < 4; r++)
                outg[(size_t)(rowb + r) * 512 + col] = acc[i][j][r] + bias;
        }
    }
}

// ================= rel_score: [0,496) fused-H GEMM (dbuf); [496,992) scores =================
__global__ __launch_bounds__(256)
void rel_score_k(const float* __restrict__ UV, const int* __restrict__ left,
                 const int* __restrict__ right, const float* __restrict__ Ws2,
                 const float* __restrict__ bs2, const u16* __restrict__ W2T,
                 const float* __restrict__ b2, float* __restrict__ rel,
                 float* __restrict__ score) {
    const int bid = blockIdx.x;
    const int t = threadIdx.x;
    const int wave = t >> 6, lane = t & 63;

    if (bid < 496) {
        // rel[m0+128, n0+128] = relu(U'[l] + V[r]) @ W2 + b2   (U' has b1 folded)
        __shared__ __align__(16) u16 As[2][128 * 32];
        __shared__ __align__(16) u16 Bs[2][128 * 32];
        const int m0 = (bid >> 2) * 128;
        const int n0 = (bid & 3) * 128;
        const int wm = (wave >> 1) * 64, wn = (wave & 1) * 64;
        const int l15 = lane & 15, quad = lane >> 4;

        // A role: thread t -> row arow = t>>1, k-half kh = t&1 (16 elems)
        const int arow = t >> 1;
        const int kh = t & 1;
        const int li = left[m0 + arow], ri = right[m0 + arow];
        const float4* Up = (const float4*)(UV + (size_t)li * 512 + kh * 16);
        const float4* Vp = (const float4*)(UV + 262144 + (size_t)ri * 512 + kh * 16);
        // A write slots (XOR-4 swizzle): logical k8 in {2kh, 2kh+1}
        const int sA0 = arow * 4 + ((kh * 2) ^ (arow & 3));
        const int sA1 = arow * 4 + ((kh * 2 + 1) ^ (arow & 3));
        // B staging: wave w chunks 2w,2w+1; row = c*16 + (l>>2), k8 = (l&3)^((l>>2)&3)
        const int browl = lane >> 2;
        const int bk8 = (lane & 3) ^ (browl & 3);
        const u16* gB0 = W2T + (size_t)(n0 + wave * 32 + browl) * 512 + bk8 * 8;
        const u16* gB1 = W2T + (size_t)(n0 + wave * 32 + 16 + browl) * 512 + bk8 * 8;
        const int lofs0 = wave * 1024, lofs1 = wave * 1024 + 512;

        floatx4 acc[4][4] = {};
        float4 uu[4], vv[4];
#pragma unroll
        for (int j = 0; j < 4; j++) { uu[j] = Up[j]; vv[j] = Vp[j]; }
        // stage step 0
        async_ld16(gB0, Bs[0] + lofs0);
        async_ld16(gB1, Bs[0] + lofs1);
        {
            uint4 h0, h1;
            h0.x = pack2(fmaxf(uu[0].x + vv[0].x, 0.f), fmaxf(uu[0].y + vv[0].y, 0.f));
            h0.y = pack2(fmaxf(uu[0].z + vv[0].z, 0.f), fmaxf(uu[0].w + vv[0].w, 0.f));
            h0.z = pack2(fmaxf(uu[1].x + vv[1].x, 0.f), fmaxf(uu[1].y + vv[1].y, 0.f));
            h0.w = pack2(fmaxf(uu[1].z + vv[1].z, 0.f), fmaxf(uu[1].w + vv[1].w, 0.f));
            h1.x = pack2(fmaxf(uu[2].x + vv[2].x, 0.f), fmaxf(uu[2].y + vv[2].y, 0.f));
            h1.y = pack2(fmaxf(uu[2].z + vv[2].z, 0.f), fmaxf(uu[2].w + vv[2].w, 0.f));
            h1.z = pack2(fmaxf(uu[3].x + vv[3].x, 0.f), fmaxf(uu[3].y + vv[3].y, 0.f));
            h1.w = pack2(fmaxf(uu[3].z + vv[3].z, 0.f), fmaxf(uu[3].w + vv[3].w, 0.f));
            *(uint4*)(As[0] + sA0 * 8) = h0;
            *(uint4*)(As[0] + sA1 * 8) = h1;
        }
#pragma unroll
        for (int j = 0; j < 4; j++) { uu[j] = Up[8 + j]; vv[j] = Vp[8 + j]; }

        for (int i = 0; i < 16; i++) {
            const int cur = i & 1;
            __syncthreads();                   // buf[cur] ready; buf[cur^1] free
            if (i + 1 < 16) {
                const int k1 = (i + 1) * 32;
                async_ld16(gB0 + k1, Bs[cur ^ 1] + lofs0);
                async_ld16(gB1 + k1, Bs[cur ^ 1] + lofs1);
                uint4 h0, h1;
                h0.x = pack2(fmaxf(uu[0].x + vv[0].x, 0.f), fmaxf(uu[0].y + vv[0].y, 0.f));
                h0.y = pack2(fmaxf(uu[0].z + vv[0].z, 0.f), fmaxf(uu[0].w + vv[0].w, 0.f));
                h0.z = pack2(fmaxf(uu[1].x + vv[1].x, 0.f), fmaxf(uu[1].y + vv[1].y, 0.f));
                h0.w = pack2(fmaxf(uu[1].z + vv[1].z, 0.f), fmaxf(uu[1].w + vv[1].w, 0.f));
                h1.x = pack2(fmaxf(uu[2].x + vv[2].x, 0.f), fmaxf(uu[2].y + vv[2].y, 0.f));
                h1.y = pack2(fmaxf(uu[2].z + vv[2].z, 0.f), fmaxf(uu[2].w + vv[2].w, 0.f));
                h1.z = pack2(fmaxf(uu[3].x + vv[3].x, 0.f), fmaxf(uu[3].y + vv[3].y, 0.f));
                h1.w = pack2(fmaxf(uu[3].z + vv[3].z, 0.f), fmaxf(uu[3].w + vv[3].w, 0.f));
                *(uint4*)(As[cur ^ 1] + sA0 * 8) = h0;
                *(uint4*)(As[cur ^ 1] + sA1 * 8) = h1;
                if (i + 2 < 16) {
                    const int q = (i + 2) * 8;
#pragma unroll
                    for (int j = 0; j < 4; j++) { uu[j] = Up[q + j]; vv[j] = Vp[q + j]; }
                }
            }
            const u16* Ac = As[cur];
            const u16* Bc = Bs[cur];
            short8 af[4], bf[4];
#pragma unroll
            for (int i2 = 0; i2 < 4; i2++) {
                const int ra = wm + i2 * 16 + l15;
                af[i2] = *(const short8*)(Ac + (ra * 4 + (quad ^ (ra & 3))) * 8);
                const int rb = wn + i2 * 16 + l15;
                bf[i2] = *(const short8*)(Bc + (rb * 4 + (quad ^ (rb & 3))) * 8);
            }
#pragma unroll
            for (int i2 = 0; i2 < 4; i2++)
#pragma unroll
                for (int j2 = 0; j2 < 4; j2++)
                    acc[i2][j2] = __builtin_amdgcn_mfma_f32_16x16x32_bf16(af[i2], bf[j2], acc[i2][j2], 0, 0, 0);
        }
#pragma unroll
        for (int j = 0; j < 4; j++) {
            const int col = n0 + wn + j * 16 + l15;
            const float bias = b2[col];
#pragma unroll
            for (int i = 0; i < 4; i++) {
                const int rowb = m0 + wm + i * 16 + quad * 4;
#pragma unroll
                for (int r = 0; r < 4; r++)
                    rel[(size_t)(rowb + r) * 512 + col] = acc[i][j][r] + bias;
            }
        }
    } else {
        // scores: 32 pairs/block, 8/wave.  Us' has bs1 folded.
        const int pid0 = (bid - 496) * 32 + wave * 8;
        const float4* Wsp = (const float4*)(Ws2 + lane * 8);
        const float4 w0 = Wsp[0], w1 = Wsp[1];
        const float bias = bs2[0];
#pragma unroll
        for (int it = 0; it < 8; it++) {
            const int p = pid0 + it;
            const int l = left[p], r = right[p];
            const float4* us = (const float4*)(UV + 2 * 262144 + (size_t)l * 512 + lane * 8);
            const float4* vs = (const float4*)(UV + 3 * 262144 + (size_t)r * 512 + lane * 8);
            const float4 a0 = us[0], a1 = us[1];
            const float4 c0 = vs[0], c1 = vs[1];
            float acc;
            acc  = fmaxf(a0.x + c0.x, 0.f) * w0.x;
            acc += fmaxf(a0.y + c0.y, 0.f) * w0.y;
            acc += fmaxf(a0.z + c0.z, 0.f) * w0.z;
            acc += fmaxf(a0.w + c0.w, 0.f) * w0.w;
            acc += fmaxf(a1.x + c1.x, 0.f) * w1.x;
            acc += fmaxf(a1.y + c1.y, 0.f) * w1.y;
            acc += fmaxf(a1.z + c1.z, 0.f) * w1.z;
            acc += fmaxf(a1.w + c1.w, 0.f) * w1.w;
#pragma unroll
            for (int off = 32; off; off >>= 1) acc += __shfl_down(acc, off, 64);
            if (lane == 0) score[p] = fabsf(acc + bias);
        }
    }
}

extern "C" void kernel_launch(void* const* d_in, const int* in_sizes, int n_in,
                              void* d_out, int out_size, void* d_ws, size_t ws_size,
                              hipStream_t stream) {
    const float* x   = (const float*)d_in[0];
    const int* ann   = (const int*)d_in[3];
    const int* left  = (const int*)d_in[5];
    const int* right = (const int*)d_in[6];
    const float* W1  = (const float*)d_in[7];
    const float* b1  = (const float*)d_in[8];
    const float* W2  = (const float*)d_in[9];
    const float* b2  = (const float*)d_in[10];
    const float* Ws1 = (const float*)d_in[11];
    const float* bs1 = (const float*)d_in[12];
    const float* Ws2 = (const float*)d_in[13];
    const float* bs2 = (const float*)d_in[14];

    float* out = (float*)d_out;
    float* entF = out;                       // output 0 (exact fp32 copy)
    float* rel  = out + OUT_ENT;             // output 1
    float* sco  = out + OUT_ENT + OUT_REL;   // output 2

    u16* W1T  = (u16*)d_ws;                  // 512*3072 bf16 (B^T)
    u16* Ws1T = W1T + 512 * 3072;
    u16* W2T  = Ws1T + 512 * 3072;           // 512*512 bf16
    u16* EntB = W2T + 512 * 512;             // 512*1536 bf16
    float* UV = (float*)(EntB + 512 * 1536); // [4][512][512] fp32: U+b1, V, Us+bs1, Vs

    prep_k<<<3840, 256, 0, stream>>>(W1, Ws1, W2, x, ann, W1T, Ws1T, W2T, entF, EntB);
    gemm_uv<<<256, 256, 0, stream>>>(EntB, W1T, Ws1T, b1, bs1, UV);
    rel_score_k<<<992, 256, 0, stream>>>(UV, left, right, Ws2, bs2, W2T, b2, rel, sco);
}